// Round 11
// baseline (212.615 us; speedup 1.0000x reference)
//
#include <hip/hip_runtime.h>
#include <hip/hip_bf16.h>

#define Bn   4096
#define Sn   128
#define En   768
#define HIDn 384
#define NHn  9
#define NEn  5
#define MAXTILES 41       // max padded m-tiles: 32 + up to 8 from per-cat rounding
#define NGEMM (480 + 3 * MAXTILES)   // 603 gemm blocks

typedef __attribute__((ext_vector_type(8))) short short8;
typedef __attribute__((ext_vector_type(4))) float f32x4;

__device__ __forceinline__ unsigned short f2bf(float v) {
  unsigned int x = __float_as_uint(v);
  x += 0x7fffu + ((x >> 16) & 1u);   // RNE
  return (unsigned short)(x >> 16);
}
__device__ __forceinline__ float dot4v(f32x4 a, f32x4 b) {
  return fmaf(a.x, b.x, fmaf(a.y, b.y, fmaf(a.z, b.z, a.w * b.w)));
}
__device__ __forceinline__ f32x4 ntl(const f32x4* p) {
  return __builtin_nontemporal_load(p);   // streaming read, no L2 reuse
}

#if defined(__has_builtin) && __has_builtin(__builtin_amdgcn_global_load_lds)
#define HAVE_GLOAD_LDS 1
// async global->LDS: lane l reads 16B at g+l*8 ushorts, HW writes ldsbase+l*16B
__device__ __forceinline__ void gload16(const unsigned short* g, unsigned short* l) {
  __builtin_amdgcn_global_load_lds(
      (const __attribute__((address_space(1))) unsigned int*)g,
      (__attribute__((address_space(3))) unsigned int*)l, 16, 0, 0);
}
#else
#define HAVE_GLOAD_LDS 0
#endif

// process one feature row held in x0..x2 (12 floats/lane across 64 lanes)
#define PROC(x0, x1, x2) {                                                 \
    float part = dot4v(x0, aw0) + dot4v(x1, aw1) + dot4v(x2, aw2);         \
    _Pragma("unroll")                                                      \
    for (int off = 32; off; off >>= 1) part += __shfl_xor(part, off);      \
    float w = __expf(part);               /* |score| small: no max-sub */  \
    lsum += w;                                                             \
    p0 += w * (x0); p1 += w * (x1); p2 += w * (x2); }

// ====== K1: pool (blocks 0..4095) | pack (4096..6111) | sort (6112) =========
__global__ __launch_bounds__(256) void prep_kernel(
    const float* __restrict__ feature, const int* __restrict__ masks,
    const float* __restrict__ attn_w, const float* __restrict__ ew,
    const float* __restrict__ g1, const int* __restrict__ category,
    unsigned short* __restrict__ pooled, unsigned short* __restrict__ Bpe,
    unsigned short* __restrict__ Bpg, int* __restrict__ rowsamp,
    int* __restrict__ meta, int* __restrict__ donec) {
  __shared__ __align__(16) union {
    struct { float pbuf[4][768]; float sbuf[4];
             int wmask[4]; int rowlist[128]; } pool;
    struct { int hist[NHn][256]; int padbase[NHn]; int total[NHn];
             int tilecat[MAXTILES]; int padTiles; } srt;
  } sm;
  const int t = threadIdx.x, lane = t & 63, wid = t >> 6;
  const int bid = blockIdx.x;

  if (bid < Bn) {                          // ---------------- pool ----------
    const int b = bid;
    const f32x4* aw = (const f32x4*)attn_w;
    const f32x4 aw0 = aw[lane], aw1 = aw[64 + lane], aw2 = aw[128 + lane];
    const f32x4* fb = (const f32x4*)(feature + (size_t)b * (Sn * En));
    unsigned int mymask = (unsigned int)
        __ballot(lane < 32 && masks[b * Sn + wid * 32 + (lane & 31)] != 0);
    if (lane == 0) sm.pool.wmask[wid] = (int)mymask;
    __syncthreads();
    const unsigned int m0m = (unsigned int)sm.pool.wmask[0];
    const unsigned int m1m = (unsigned int)sm.pool.wmask[1];
    const unsigned int m2m = (unsigned int)sm.pool.wmask[2];
    const unsigned int m3m = (unsigned int)sm.pool.wmask[3];
    const int c0c = __popc(m0m), c1c = __popc(m1m), c2c = __popc(m2m);
    const int nr = c0c + c1c + c2c + __popc(m3m);
    const int mybase = (wid > 0 ? c0c : 0) + (wid > 1 ? c1c : 0) + (wid > 2 ? c2c : 0);
    if (lane < 32 && ((mymask >> lane) & 1u))
      sm.pool.rowlist[mybase + __popc(mymask & ((1u << lane) - 1u))] = wid * 32 + lane;
    __syncthreads();
    f32x4 p0 = {0,0,0,0}, p1 = {0,0,0,0}, p2 = {0,0,0,0};
    float lsum = 0.f;
    int j = wid;                           // interleaved: wave w takes w, w+4, ...
    if (j < nr) {                          // 3-deep load pipeline
      const f32x4* rp = fb + sm.pool.rowlist[j] * 192;
      f32x4 a0 = ntl(rp + lane), a1 = ntl(rp + 64 + lane), a2 = ntl(rp + 128 + lane);
      if (j + 4 < nr) {
        const f32x4* rq = fb + sm.pool.rowlist[j + 4] * 192;
        f32x4 b0 = ntl(rq + lane), b1 = ntl(rq + 64 + lane), b2 = ntl(rq + 128 + lane);
        for (int jj = j + 8; jj < nr; jj += 4) {
          const f32x4* rr = fb + sm.pool.rowlist[jj] * 192;
          f32x4 n0 = ntl(rr + lane), n1 = ntl(rr + 64 + lane), n2 = ntl(rr + 128 + lane);
          PROC(a0, a1, a2);
          a0 = b0; a1 = b1; a2 = b2;
          b0 = n0; b1 = n1; b2 = n2;
        }
        PROC(a0, a1, a2);
        a0 = b0; a1 = b1; a2 = b2;
      }
      PROC(a0, a1, a2);
    }
    ((f32x4*)sm.pool.pbuf[wid])[lane] = p0;
    ((f32x4*)sm.pool.pbuf[wid])[64 + lane] = p1;
    ((f32x4*)sm.pool.pbuf[wid])[128 + lane] = p2;
    if (lane == 0) sm.pool.sbuf[wid] = lsum;
    __syncthreads();
    float total = sm.pool.sbuf[0] + sm.pool.sbuf[1] + sm.pool.sbuf[2] + sm.pool.sbuf[3];
    if (total == 0.f) {                    // all rows masked: uniform alpha
      p0 = p1 = p2 = f32x4{0,0,0,0};
      for (int s = 0; s < 32; ++s) {
        const f32x4* rp = fb + (wid * 32 + s) * 192;
        p0 += ntl(rp + lane); p1 += ntl(rp + 64 + lane); p2 += ntl(rp + 128 + lane);
      }
      ((f32x4*)sm.pool.pbuf[wid])[lane] = p0;
      ((f32x4*)sm.pool.pbuf[wid])[64 + lane] = p1;
      ((f32x4*)sm.pool.pbuf[wid])[128 + lane] = p2;
      __syncthreads();
      total = 128.f;
    }
    const float inv = 1.f / total;
    if (t < 192) {
      f32x4 s0 = ((const f32x4*)sm.pool.pbuf[0])[t];
      f32x4 s1 = ((const f32x4*)sm.pool.pbuf[1])[t];
      f32x4 s2 = ((const f32x4*)sm.pool.pbuf[2])[t];
      f32x4 s3 = ((const f32x4*)sm.pool.pbuf[3])[t];
      f32x4 smv = (s0 + s1) + (s2 + s3);
      ushort4 u4;
      u4.x = f2bf(smv.x * inv); u4.y = f2bf(smv.y * inv);
      u4.z = f2bf(smv.z * inv); u4.w = f2bf(smv.w * inv);
      ((ushort4*)pooled)[(size_t)b * 192 + t] = u4;
    }
    return;
  }

  if (bid < Bn + 2016) {                   // ---------------- pack ----------
    const int pair = (bid - Bn) * 4 + wid;
    const int q = lane >> 4, j = lane & 15;
    const float* src; unsigned short* dst; int kt;
    if (pair < 2880) {                     // expert: 120 ntiles x 24 kt
      int nt = pair / 24; kt = pair % 24;
      int col = nt * 16 + j;
      src = ew + (size_t)(col / HIDn) * (En * HIDn) + (col % HIDn);
      dst = Bpe + (size_t)pair * 512;
    } else {                               // gate: 9 heads x 24 ntiles x 24 kt
      int g = pair - 2880;
      int h = g / 576, rem = g % 576;
      int nt = rem / 24; kt = rem % 24;
      int col = nt * 16 + j;
      src = g1 + (size_t)h * (En * HIDn) + col;
      dst = Bpg + ((size_t)(h * 24 + nt) * 24 + kt) * 512;
    }
    unsigned short outv[8] __attribute__((aligned(16)));
    #pragma unroll
    for (int e = 0; e < 8; ++e) {
      int k = kt * 32 + q * 8 + e;
      outv[e] = f2bf(src[(size_t)k * HIDn]);
    }
    *(uint4*)&dst[lane * 8] = *(const uint4*)outv;
    return;
  }

  // -------- sort: stable counting sort by category, 128-padded tiles -------
  if (t == 0) donec[0] = 0;                // reset gemm completion counter
  #pragma unroll
  for (int jj = 0; jj < NHn; ++jj) sm.srt.hist[jj][t] = 0;
  __syncthreads();
  for (int i = 0; i < 16; ++i) { int c = category[t * 16 + i]; sm.srt.hist[c][t]++; }
  __syncthreads();
  if (t < NHn) {
    int run = 0;
    for (int x = 0; x < 256; ++x) { int v = sm.srt.hist[t][x]; sm.srt.hist[t][x] = run; run += v; }
    sm.srt.total[t] = run;
  }
  __syncthreads();
  if (t == 0) {
    int pb = 0, mt = 0;
    for (int jj = 0; jj < NHn; ++jj) {
      sm.srt.padbase[jj] = pb;
      int tot = sm.srt.total[jj];
      int nt = (tot + 127) >> 7;
      for (int k2 = 0; k2 < nt; ++k2) {
        meta[1 + mt + k2] = jj;
        int vv = tot - (k2 << 7); if (vv > 128) vv = 128;
        meta[64 + mt + k2] = vv;
        sm.srt.tilecat[mt + k2] = jj;
      }
      mt += nt; pb += nt << 7;
    }
    meta[0] = mt; sm.srt.padTiles = mt;
  }
  __syncthreads();
  const int padM = sm.srt.padTiles << 7;
  for (int mm = t; mm < padM; mm += 256) {
    int h = sm.srt.tilecat[mm >> 7];
    if (mm - sm.srt.padbase[h] >= sm.srt.total[h]) rowsamp[mm] = 0;
  }
  for (int i = 0; i < 16; ++i) {           // stable scatter
    int idx = t * 16 + i; int c = category[idx];
    int off = sm.srt.hist[c][t]++;
    rowsamp[sm.srt.padbase[c] + off] = idx;
  }
}

// ====== K2: gemmg (blocks 0..122) | gemme (123..602) + fused finale ========
// BK=64 K-steps (12 iters, 24 barriers), B staged via global_load_lds.
// Last 16 blocks to finish perform the gate-softmax+combine+sigmoid finale.
__global__ __launch_bounds__(256) void gemm_kernel(
    const unsigned short* __restrict__ pooled, const unsigned short* __restrict__ Bpe,
    const unsigned short* __restrict__ Bpg, const float* __restrict__ eb,
    const float* __restrict__ gb1, const float* __restrict__ g2,
    const int* __restrict__ category, const float* __restrict__ hw,
    const int* __restrict__ rowsamp, const int* __restrict__ meta,
    const float* __restrict__ gb2, const float* __restrict__ hb,
    float* __restrict__ partial, float* __restrict__ glogp,
    int* __restrict__ donec, float* __restrict__ out) {
  __shared__ __align__(16) struct {
    unsigned short Alds[128 * 72];         // 18,432 B (rows padded 64->72)
    unsigned short Blds[8 * 1024];         // 16,384 B (8 subtiles x 2 k-halves)
    union {
      struct { float plds[2][128]; } e;
      struct { int rs[128]; float w2[640]; } g;
    } u;
  } sm;
  __shared__ int myord;
  const int t = threadIdx.x, lane = t & 63, wid = t >> 6;
  const int wm = wid >> 1, wn = wid & 1;
  const int bid = blockIdx.x;
  const int arow = wm * 64 + (lane & 15);
  const int aq = (lane >> 4) * 8;
  const int lrb = wm * 64 + ((lane >> 4) << 2);
  const int cb = wn * 64 + (lane & 15);
  const int srow = t >> 3, scol = (t & 7) * 8;   // A staging map
  f32x4 acc[4][4] = {};

  if (bid < 3 * MAXTILES) {                // -------------- gemmg ----------
    const int mt = bid / 3, bxg = bid % 3;
    if (mt < meta[0]) {
      const int h = meta[1 + mt], valid = meta[64 + mt];
      if (t < 128) sm.u.g.rs[t] = rowsamp[mt * 128 + t];
      const float* w2src = g2 + ((size_t)h * HIDn + bxg * 128) * 5;
      for (int idx = t; idx < 640; idx += 256) sm.u.g.w2[idx] = w2src[idx];
      __syncthreads();                     // rs ready for staging
      for (int kt2 = 0; kt2 < 12; ++kt2) {
        __syncthreads();
        #pragma unroll
        for (int i = 0; i < 4; ++i) {      // B: async frag-linear
          int chunk = wid * 4 + i, st = chunk >> 1, ks = chunk & 1;
#if HAVE_GLOAD_LDS
          gload16(&Bpg[(((size_t)h * 24 + bxg * 8 + st) * 24 + kt2 * 2 + ks) * 512 + lane * 8],
                  &sm.Blds[st * 1024 + ks * 512]);
#else
          *(uint4*)&sm.Blds[st * 1024 + ks * 512 + lane * 8] =
              *(const uint4*)&Bpg[(((size_t)h * 24 + bxg * 8 + st) * 24 + kt2 * 2 + ks) * 512 + lane * 8];
#endif
        }
        #pragma unroll
        for (int rr = 0; rr < 4; ++rr) {   // A: gathered rows
          int row = srow + rr * 32;
          *(uint4*)&sm.Alds[row * 72 + scol] =
              *(const uint4*)&pooled[(size_t)sm.u.g.rs[row] * En + kt2 * 64 + scol];
        }
        __syncthreads();
        #pragma unroll
        for (int ks = 0; ks < 2; ++ks) {
          short8 af[4], bfv[4];
          #pragma unroll
          for (int i = 0; i < 4; ++i)
            af[i] = *(const short8*)&sm.Alds[(arow + i * 16) * 72 + ks * 32 + aq];
          #pragma unroll
          for (int j = 0; j < 4; ++j)
            bfv[j] = *(const short8*)&sm.Blds[(wn * 4 + j) * 1024 + ks * 512 + lane * 8];
          #pragma unroll
          for (int i = 0; i < 4; ++i)
            #pragma unroll
            for (int j = 0; j < 4; ++j)
              acc[i][j] = __builtin_amdgcn_mfma_f32_16x16x32_bf16(af[i], bfv[j], acc[i][j], 0, 0, 0);
        }
      }
      #pragma unroll
      for (int i = 0; i < 4; ++i) {
        #pragma unroll
        for (int rr = 0; rr < 4; ++rr) {
          const int lrow = lrb + i * 16 + rr;
          float s[5] = {0.f, 0.f, 0.f, 0.f, 0.f};
          #pragma unroll
          for (int jj = 0; jj < 4; ++jj) {
            int cl = cb + jj * 16;
            float v = acc[i][jj][rr] + gb1[h * HIDn + bxg * 128 + cl];
            v = fmaxf(v, 0.f);
            #pragma unroll
            for (int k = 0; k < 5; ++k) s[k] = fmaf(v, sm.u.g.w2[cl * 5 + k], s[k]);
          }
          #pragma unroll
          for (int k = 0; k < 5; ++k)
            #pragma unroll
            for (int off = 8; off; off >>= 1) s[k] += __shfl_xor(s[k], off);
          if ((lane & 15) == 0 && lrow < valid) {
            int samp = sm.u.g.rs[lrow];
            #pragma unroll
            for (int k = 0; k < 5; ++k)
              glogp[((size_t)bxg * Bn + samp) * 5 + k] = s[k];
          }
        }
      }
    }
  } else {                                 // -------------- gemme ----------
    const int e = bid - 3 * MAXTILES;
    const int bx = e % 15, by = e / 15;
    const int m0 = by * 128, ntg0 = bx * 8;
    for (int kt2 = 0; kt2 < 12; ++kt2) {
      __syncthreads();
      #pragma unroll
      for (int i = 0; i < 4; ++i) {        // B: async frag-linear
        int chunk = wid * 4 + i, st = chunk >> 1, ks = chunk & 1;
#if HAVE_GLOAD_LDS
        gload16(&Bpe[((size_t)(ntg0 + st) * 24 + kt2 * 2 + ks) * 512 + lane * 8],
                &sm.Blds[st * 1024 + ks * 512]);
#else
        *(uint4*)&sm.Blds[st * 1024 + ks * 512 + lane * 8] =
            *(const uint4*)&Bpe[((size_t)(ntg0 + st) * 24 + kt2 * 2 + ks) * 512 + lane * 8];
#endif
      }
      #pragma unroll
      for (int rr = 0; rr < 4; ++rr) {     // A: contiguous rows
        int row = srow + rr * 32;
        *(uint4*)&sm.Alds[row * 72 + scol] =
            *(const uint4*)&pooled[(size_t)(m0 + row) * En + kt2 * 64 + scol];
      }
      __syncthreads();
      #pragma unroll
      for (int ks = 0; ks < 2; ++ks) {
        short8 af[4], bfv[4];
        #pragma unroll
        for (int i = 0; i < 4; ++i)
          af[i] = *(const short8*)&sm.Alds[(arow + i * 16) * 72 + ks * 32 + aq];
        #pragma unroll
        for (int j = 0; j < 4; ++j)
          bfv[j] = *(const short8*)&sm.Blds[(wn * 4 + j) * 1024 + ks * 512 + lane * 8];
        #pragma unroll
        for (int i = 0; i < 4; ++i)
          #pragma unroll
          for (int j = 0; j < 4; ++j)
            acc[i][j] = __builtin_amdgcn_mfma_f32_16x16x32_bf16(af[i], bfv[j], acc[i][j], 0, 0, 0);
      }
    }
    const int lcolbase = (bx % 3) * 128;
    float sums[4][4];
    #pragma unroll
    for (int i = 0; i < 4; ++i) {
      #pragma unroll
      for (int rr = 0; rr < 4; ++rr) {
        const int row = m0 + lrb + i * 16 + rr;
        const int cat = category[row];
        float s = 0.f;
        #pragma unroll
        for (int jj = 0; jj < 4; ++jj) {
          int cl = cb + jj * 16;
          float v = acc[i][jj][rr] + eb[bx * 128 + cl];
          v = fmaxf(v, 0.f);
          s = fmaf(v, hw[cat * HIDn + lcolbase + cl], s);
        }
        #pragma unroll
        for (int off = 8; off; off >>= 1) s += __shfl_xor(s, off);
        sums[i][rr] = s;
      }
    }
    __syncthreads();
    if ((lane & 15) == 0) {
      #pragma unroll
      for (int i = 0; i < 4; ++i)
        #pragma unroll
        for (int rr = 0; rr < 4; ++rr)
          sm.u.e.plds[wn][lrb + i * 16 + rr] = sums[i][rr];
    }
    __syncthreads();
    if (t < 128) partial[(size_t)bx * Bn + m0 + t] = sm.u.e.plds[0][t] + sm.u.e.plds[1][t];
  }

  // ---- finale: last 16 finishing blocks compute softmax+combine+sigmoid ----
  __syncthreads();
  if (t == 0) {
    __threadfence();                       // publish this block's writes
    myord = __hip_atomic_fetch_add(donec, 1, __ATOMIC_ACQ_REL, __HIP_MEMORY_SCOPE_AGENT);
  }
  __syncthreads();
  const int ord = myord;
  if (ord >= NGEMM - 16) {
    if (t == 0) {
      while (__hip_atomic_load(donec, __ATOMIC_RELAXED, __HIP_MEMORY_SCOPE_AGENT) < NGEMM)
        __builtin_amdgcn_s_sleep(16);
    }
    __syncthreads();
    __threadfence();                       // acquire: see all blocks' writes
    const int slice = ord - (NGEMM - 16);
    const int row = slice * 256 + t;
    const int cat = category[row];
    float gl[5];
    #pragma unroll
    for (int k = 0; k < 5; ++k)
      gl[k] = gb2[cat * 5 + k]
            + glogp[((size_t)0 * Bn + row) * 5 + k]
            + glogp[((size_t)1 * Bn + row) * 5 + k]
            + glogp[((size_t)2 * Bn + row) * 5 + k];
    float mx = fmaxf(fmaxf(fmaxf(gl[0], gl[1]), fmaxf(gl[2], gl[3])), gl[4]);
    float ek[5], es = 0.f;
    #pragma unroll
    for (int k = 0; k < 5; ++k) { ek[k] = __expf(gl[k] - mx); es += ek[k]; }
    const float einv = 1.f / es;
    float s = 0.f;
    #pragma unroll
    for (int k = 0; k < 5; ++k) {
      float ps = partial[(size_t)(3 * k) * Bn + row]
               + partial[(size_t)(3 * k + 1) * Bn + row]
               + partial[(size_t)(3 * k + 2) * Bn + row];
      s = fmaf(ek[k] * einv, ps, s);
    }
    s += hb[cat];
    out[row] = 1.f / (1.f + __expf(-s));
  }
}

extern "C" void kernel_launch(void* const* d_in, const int* in_sizes, int n_in,
                              void* d_out, int out_size, void* d_ws, size_t ws_size,
                              hipStream_t stream) {
  const float* feature  = (const float*)d_in[0];
  const int*   masks    = (const int*)d_in[1];
  const int*   category = (const int*)d_in[2];
  const float* attn_w   = (const float*)d_in[3];
  // d_in[4] attn_b cancels in softmax
  const float* gate_w1  = (const float*)d_in[5];
  const float* gate_b1  = (const float*)d_in[6];
  const float* gate_w2  = (const float*)d_in[7];
  const float* gate_b2  = (const float*)d_in[8];
  const float* expert_w = (const float*)d_in[9];
  const float* expert_b = (const float*)d_in[10];
  const float* head_w   = (const float*)d_in[11];
  const float* head_b   = (const float*)d_in[12];
  float* out = (float*)d_out;

  char* ws = (char*)d_ws;
  unsigned short* pooled = (unsigned short*)(ws);             //  6,291,456 B
  unsigned short* Bpe    = (unsigned short*)(ws + 6291456);   //  2,949,120 B
  unsigned short* Bpg    = (unsigned short*)(ws + 9240576);   //  5,308,416 B
  int* rowsamp           = (int*)(ws + 14548992);             //     20,992 B
  int* meta              = (int*)(ws + 14569984);             //        512 B
  float* glogp           = (float*)(ws + 14570496);           //    245,760 B
  float* partial         = (float*)(ws + 14816256);           //    245,760 B
  int* donec             = (int*)(ws + 15062016);             //        256 B

  prep_kernel<<<dim3(Bn + 2016 + 1), dim3(256), 0, stream>>>(
      feature, masks, attn_w, expert_w, gate_w1, category,
      pooled, Bpe, Bpg, rowsamp, meta, donec);
  gemm_kernel<<<dim3(NGEMM), dim3(256), 0, stream>>>(
      pooled, Bpe, Bpg, expert_b, gate_b1, gate_w2, category, head_w,
      rowsamp, meta, gate_b2, head_b, partial, glogp, donec, out);
}

// Round 12
// 179.748 us; speedup vs baseline: 1.1829x; 1.1829x over previous
//
#include <hip/hip_runtime.h>
#include <hip/hip_bf16.h>

#define Bn   4096
#define Sn   128
#define En   768
#define HIDn 384
#define NHn  9
#define NEn  5
#define MAXTILES 41       // max padded m-tiles: 32 + up to 8 from per-cat rounding

typedef __attribute__((ext_vector_type(8))) short short8;
typedef __attribute__((ext_vector_type(4))) float f32x4;

__device__ __forceinline__ unsigned short f2bf(float v) {
  unsigned int x = __float_as_uint(v);
  x += 0x7fffu + ((x >> 16) & 1u);   // RNE
  return (unsigned short)(x >> 16);
}
__device__ __forceinline__ float dot4v(f32x4 a, f32x4 b) {
  return fmaf(a.x, b.x, fmaf(a.y, b.y, fmaf(a.z, b.z, a.w * b.w)));
}
__device__ __forceinline__ f32x4 ntl(const f32x4* p) {
  return __builtin_nontemporal_load(p);   // streaming read, no L2 reuse
}

#if defined(__has_builtin) && __has_builtin(__builtin_amdgcn_global_load_lds)
#define HAVE_GLOAD_LDS 1
// async global->LDS: lane l reads 16B at g+l*8 ushorts, HW writes ldsbase+l*16B
__device__ __forceinline__ void gload16(const unsigned short* g, unsigned short* l) {
  __builtin_amdgcn_global_load_lds(
      (const __attribute__((address_space(1))) unsigned int*)g,
      (__attribute__((address_space(3))) unsigned int*)l, 16, 0, 0);
}
#else
#define HAVE_GLOAD_LDS 0
#endif

// process one feature row held in x0..x2 (12 floats/lane across 64 lanes)
#define PROC(x0, x1, x2) {                                                 \
    float part = dot4v(x0, aw0) + dot4v(x1, aw1) + dot4v(x2, aw2);         \
    _Pragma("unroll")                                                      \
    for (int off = 32; off; off >>= 1) part += __shfl_xor(part, off);      \
    float w = __expf(part);               /* |score| small: no max-sub */  \
    lsum += w;                                                             \
    p0 += w * (x0); p1 += w * (x1); p2 += w * (x2); }

// ====== K1: pool (blocks 0..4095) | pack (4096..6111) | sort (6112) =========
__global__ __launch_bounds__(256) void prep_kernel(
    const float* __restrict__ feature, const int* __restrict__ masks,
    const float* __restrict__ attn_w, const float* __restrict__ ew,
    const float* __restrict__ g1, const int* __restrict__ category,
    unsigned short* __restrict__ pooled, unsigned short* __restrict__ Bpe,
    unsigned short* __restrict__ Bpg, int* __restrict__ rowsamp,
    int* __restrict__ meta) {
  __shared__ __align__(16) union {
    struct { float pbuf[4][768]; float sbuf[4]; } pool;
    struct { int hist[NHn][256]; int padbase[NHn]; int total[NHn];
             int tilecat[MAXTILES]; int padTiles; } srt;
  } sm;
  const int t = threadIdx.x, lane = t & 63, wid = t >> 6;
  const int bid = blockIdx.x;

  if (bid < Bn) {                          // ---------------- pool ----------
    const int b = bid;
    const f32x4* aw = (const f32x4*)attn_w;
    const f32x4 aw0 = aw[lane], aw1 = aw[64 + lane], aw2 = aw[128 + lane];
    const f32x4* fb = (const f32x4*)(feature + (size_t)b * (Sn * En));
    unsigned long long bal = __ballot(lane < 32 && masks[b * Sn + wid * 32 + (lane & 31)] != 0);
    unsigned int m = (unsigned int)bal;
    const int rowbase = wid * 32;
    f32x4 p0 = {0,0,0,0}, p1 = {0,0,0,0}, p2 = {0,0,0,0};
    float lsum = 0.f;
    if (m) {                               // 2-deep software pipeline
      int s = __builtin_ctz(m); m &= m - 1;
      const f32x4* rp = fb + (rowbase + s) * 192;
      f32x4 a0 = ntl(rp + lane), a1 = ntl(rp + 64 + lane), a2 = ntl(rp + 128 + lane);
      if (m) {
        int s2 = __builtin_ctz(m); m &= m - 1;
        const f32x4* rq = fb + (rowbase + s2) * 192;
        f32x4 b0 = ntl(rq + lane), b1 = ntl(rq + 64 + lane), b2 = ntl(rq + 128 + lane);
        while (m) {
          int s3 = __builtin_ctz(m); m &= m - 1;
          const f32x4* rr = fb + (rowbase + s3) * 192;
          f32x4 n0 = ntl(rr + lane), n1 = ntl(rr + 64 + lane), n2 = ntl(rr + 128 + lane);
          PROC(a0, a1, a2);
          a0 = b0; a1 = b1; a2 = b2;
          b0 = n0; b1 = n1; b2 = n2;
        }
        PROC(a0, a1, a2);
        a0 = b0; a1 = b1; a2 = b2;
      }
      PROC(a0, a1, a2);
    }
    ((f32x4*)sm.pool.pbuf[wid])[lane] = p0;
    ((f32x4*)sm.pool.pbuf[wid])[64 + lane] = p1;
    ((f32x4*)sm.pool.pbuf[wid])[128 + lane] = p2;
    if (lane == 0) sm.pool.sbuf[wid] = lsum;
    __syncthreads();
    float total = sm.pool.sbuf[0] + sm.pool.sbuf[1] + sm.pool.sbuf[2] + sm.pool.sbuf[3];
    if (total == 0.f) {                    // all rows masked: uniform alpha
      p0 = p1 = p2 = f32x4{0,0,0,0};
      for (int s = 0; s < 32; ++s) {
        const f32x4* rp = fb + (rowbase + s) * 192;
        p0 += ntl(rp + lane); p1 += ntl(rp + 64 + lane); p2 += ntl(rp + 128 + lane);
      }
      ((f32x4*)sm.pool.pbuf[wid])[lane] = p0;
      ((f32x4*)sm.pool.pbuf[wid])[64 + lane] = p1;
      ((f32x4*)sm.pool.pbuf[wid])[128 + lane] = p2;
      __syncthreads();
      total = 128.f;
    }
    const float inv = 1.f / total;
    if (t < 192) {
      f32x4 s0 = ((const f32x4*)sm.pool.pbuf[0])[t];
      f32x4 s1 = ((const f32x4*)sm.pool.pbuf[1])[t];
      f32x4 s2 = ((const f32x4*)sm.pool.pbuf[2])[t];
      f32x4 s3 = ((const f32x4*)sm.pool.pbuf[3])[t];
      f32x4 smv = (s0 + s1) + (s2 + s3);
      ushort4 u4;
      u4.x = f2bf(smv.x * inv); u4.y = f2bf(smv.y * inv);
      u4.z = f2bf(smv.z * inv); u4.w = f2bf(smv.w * inv);
      ((ushort4*)pooled)[(size_t)b * 192 + t] = u4;
    }
    return;
  }

  if (bid < Bn + 2016) {                   // ---------------- pack ----------
    const int pair = (bid - Bn) * 4 + wid;
    const int q = lane >> 4, j = lane & 15;
    const float* src; unsigned short* dst; int kt;
    if (pair < 2880) {                     // expert: 120 ntiles x 24 kt
      int nt = pair / 24; kt = pair % 24;
      int col = nt * 16 + j;
      src = ew + (size_t)(col / HIDn) * (En * HIDn) + (col % HIDn);
      dst = Bpe + (size_t)pair * 512;
    } else {                               // gate: 9 heads x 24 ntiles x 24 kt
      int g = pair - 2880;
      int h = g / 576, rem = g % 576;
      int nt = rem / 24; kt = rem % 24;
      int col = nt * 16 + j;
      src = g1 + (size_t)h * (En * HIDn) + col;
      dst = Bpg + ((size_t)(h * 24 + nt) * 24 + kt) * 512;
    }
    unsigned short outv[8] __attribute__((aligned(16)));
    #pragma unroll
    for (int e = 0; e < 8; ++e) {
      int k = kt * 32 + q * 8 + e;
      outv[e] = f2bf(src[(size_t)k * HIDn]);
    }
    *(uint4*)&dst[lane * 8] = *(const uint4*)outv;
    return;
  }

  // -------- sort: stable counting sort by category, 128-padded tiles -------
  #pragma unroll
  for (int jj = 0; jj < NHn; ++jj) sm.srt.hist[jj][t] = 0;
  __syncthreads();
  for (int i = 0; i < 16; ++i) { int c = category[t * 16 + i]; sm.srt.hist[c][t]++; }
  __syncthreads();
  if (t < NHn) {
    int run = 0;
    for (int x = 0; x < 256; ++x) { int v = sm.srt.hist[t][x]; sm.srt.hist[t][x] = run; run += v; }
    sm.srt.total[t] = run;
  }
  __syncthreads();
  if (t == 0) {
    int pb = 0, mt = 0;
    for (int jj = 0; jj < NHn; ++jj) {
      sm.srt.padbase[jj] = pb;
      int tot = sm.srt.total[jj];
      int nt = (tot + 127) >> 7;
      for (int k2 = 0; k2 < nt; ++k2) {
        meta[1 + mt + k2] = jj;
        int vv = tot - (k2 << 7); if (vv > 128) vv = 128;
        meta[64 + mt + k2] = vv;
        sm.srt.tilecat[mt + k2] = jj;
      }
      mt += nt; pb += nt << 7;
    }
    meta[0] = mt; sm.srt.padTiles = mt;
  }
  __syncthreads();
  const int padM = sm.srt.padTiles << 7;
  for (int mm = t; mm < padM; mm += 256) {
    int h = sm.srt.tilecat[mm >> 7];
    if (mm - sm.srt.padbase[h] >= sm.srt.total[h]) rowsamp[mm] = 0;
  }
  for (int i = 0; i < 16; ++i) {           // stable scatter
    int idx = t * 16 + i; int c = category[idx];
    int off = sm.srt.hist[c][t]++;
    rowsamp[sm.srt.padbase[c] + off] = idx;
  }
}

// ====== K2: gemmg (blocks 0..122) | gemme (123..602) =======================
// BK=64 K-steps (12 iters, 24 barriers), B staged via global_load_lds
// (fragment-linear source/dest), A staged via VGPR into padded [128][72].
__global__ __launch_bounds__(256) void gemm_kernel(
    const unsigned short* __restrict__ pooled, const unsigned short* __restrict__ Bpe,
    const unsigned short* __restrict__ Bpg, const float* __restrict__ eb,
    const float* __restrict__ gb1, const float* __restrict__ g2,
    const int* __restrict__ category, const float* __restrict__ hw,
    const int* __restrict__ rowsamp, const int* __restrict__ meta,
    float* __restrict__ partial, float* __restrict__ glogp) {
  __shared__ __align__(16) struct {
    unsigned short Alds[128 * 72];         // 18,432 B (rows padded 64->72)
    unsigned short Blds[8 * 1024];         // 16,384 B (8 subtiles x 2 k-halves)
    union {
      struct { float plds[2][128]; } e;
      struct { int rs[128]; float w2[640]; } g;
    } u;
  } sm;
  const int t = threadIdx.x, lane = t & 63, wid = t >> 6;
  const int wm = wid >> 1, wn = wid & 1;
  const int bid = blockIdx.x;
  const int arow = wm * 64 + (lane & 15);
  const int aq = (lane >> 4) * 8;
  const int lrb = wm * 64 + ((lane >> 4) << 2);
  const int cb = wn * 64 + (lane & 15);
  const int srow = t >> 3, scol = (t & 7) * 8;   // A staging map
  f32x4 acc[4][4] = {};

  if (bid < 3 * MAXTILES) {                // -------------- gemmg ----------
    const int mt = bid / 3, bxg = bid % 3;
    if (mt >= meta[0]) return;
    const int h = meta[1 + mt], valid = meta[64 + mt];
    if (t < 128) sm.u.g.rs[t] = rowsamp[mt * 128 + t];
    const float* w2src = g2 + ((size_t)h * HIDn + bxg * 128) * 5;
    for (int idx = t; idx < 640; idx += 256) sm.u.g.w2[idx] = w2src[idx];
    __syncthreads();                       // rs ready for staging
    for (int kt2 = 0; kt2 < 12; ++kt2) {
      __syncthreads();
      #pragma unroll
      for (int i = 0; i < 4; ++i) {        // B: async frag-linear
        int chunk = wid * 4 + i, st = chunk >> 1, ks = chunk & 1;
#if HAVE_GLOAD_LDS
        gload16(&Bpg[(((size_t)h * 24 + bxg * 8 + st) * 24 + kt2 * 2 + ks) * 512 + lane * 8],
                &sm.Blds[st * 1024 + ks * 512]);
#else
        *(uint4*)&sm.Blds[st * 1024 + ks * 512 + lane * 8] =
            *(const uint4*)&Bpg[(((size_t)h * 24 + bxg * 8 + st) * 24 + kt2 * 2 + ks) * 512 + lane * 8];
#endif
      }
      #pragma unroll
      for (int rr = 0; rr < 4; ++rr) {     // A: gathered rows
        int row = srow + rr * 32;
        *(uint4*)&sm.Alds[row * 72 + scol] =
            *(const uint4*)&pooled[(size_t)sm.u.g.rs[row] * En + kt2 * 64 + scol];
      }
      __syncthreads();
      #pragma unroll
      for (int ks = 0; ks < 2; ++ks) {
        short8 af[4], bfv[4];
        #pragma unroll
        for (int i = 0; i < 4; ++i)
          af[i] = *(const short8*)&sm.Alds[(arow + i * 16) * 72 + ks * 32 + aq];
        #pragma unroll
        for (int j = 0; j < 4; ++j)
          bfv[j] = *(const short8*)&sm.Blds[(wn * 4 + j) * 1024 + ks * 512 + lane * 8];
        #pragma unroll
        for (int i = 0; i < 4; ++i)
          #pragma unroll
          for (int j = 0; j < 4; ++j)
            acc[i][j] = __builtin_amdgcn_mfma_f32_16x16x32_bf16(af[i], bfv[j], acc[i][j], 0, 0, 0);
      }
    }
    #pragma unroll
    for (int i = 0; i < 4; ++i) {
      #pragma unroll
      for (int rr = 0; rr < 4; ++rr) {
        const int lrow = lrb + i * 16 + rr;
        float s[5] = {0.f, 0.f, 0.f, 0.f, 0.f};
        #pragma unroll
        for (int jj = 0; jj < 4; ++jj) {
          int cl = cb + jj * 16;
          float v = acc[i][jj][rr] + gb1[h * HIDn + bxg * 128 + cl];
          v = fmaxf(v, 0.f);
          #pragma unroll
          for (int k = 0; k < 5; ++k) s[k] = fmaf(v, sm.u.g.w2[cl * 5 + k], s[k]);
        }
        #pragma unroll
        for (int k = 0; k < 5; ++k)
          #pragma unroll
          for (int off = 8; off; off >>= 1) s[k] += __shfl_xor(s[k], off);
        if ((lane & 15) == 0 && lrow < valid) {
          int samp = sm.u.g.rs[lrow];
          #pragma unroll
          for (int k = 0; k < 5; ++k)
            glogp[((size_t)bxg * Bn + samp) * 5 + k] = s[k];
        }
      }
    }
    return;
  }

  // ---------------- gemme ----------
  const int e = bid - 3 * MAXTILES;
  const int bx = e % 15, by = e / 15;
  const int m0 = by * 128, ntg0 = bx * 8;
  for (int kt2 = 0; kt2 < 12; ++kt2) {
    __syncthreads();
    #pragma unroll
    for (int i = 0; i < 4; ++i) {          // B: async frag-linear
      int chunk = wid * 4 + i, st = chunk >> 1, ks = chunk & 1;
#if HAVE_GLOAD_LDS
      gload16(&Bpe[((size_t)(ntg0 + st) * 24 + kt2 * 2 + ks) * 512 + lane * 8],
              &sm.Blds[st * 1024 + ks * 512]);
#else
      *(uint4*)&sm.Blds[st * 1024 + ks * 512 + lane * 8] =
          *(const uint4*)&Bpe[((size_t)(ntg0 + st) * 24 + kt2 * 2 + ks) * 512 + lane * 8];
#endif
    }
    #pragma unroll
    for (int rr = 0; rr < 4; ++rr) {       // A: contiguous rows
      int row = srow + rr * 32;
      *(uint4*)&sm.Alds[row * 72 + scol] =
          *(const uint4*)&pooled[(size_t)(m0 + row) * En + kt2 * 64 + scol];
    }
    __syncthreads();
    #pragma unroll
    for (int ks = 0; ks < 2; ++ks) {
      short8 af[4], bfv[4];
      #pragma unroll
      for (int i = 0; i < 4; ++i)
        af[i] = *(const short8*)&sm.Alds[(arow + i * 16) * 72 + ks * 32 + aq];
      #pragma unroll
      for (int j = 0; j < 4; ++j)
        bfv[j] = *(const short8*)&sm.Blds[(wn * 4 + j) * 1024 + ks * 512 + lane * 8];
      #pragma unroll
      for (int i = 0; i < 4; ++i)
        #pragma unroll
        for (int j = 0; j < 4; ++j)
          acc[i][j] = __builtin_amdgcn_mfma_f32_16x16x32_bf16(af[i], bfv[j], acc[i][j], 0, 0, 0);
    }
  }
  const int lcolbase = (bx % 3) * 128;
  float sums[4][4];
  #pragma unroll
  for (int i = 0; i < 4; ++i) {
    #pragma unroll
    for (int rr = 0; rr < 4; ++rr) {
      const int row = m0 + lrb + i * 16 + rr;
      const int cat = category[row];
      float s = 0.f;
      #pragma unroll
      for (int jj = 0; jj < 4; ++jj) {
        int cl = cb + jj * 16;
        float v = acc[i][jj][rr] + eb[bx * 128 + cl];
        v = fmaxf(v, 0.f);
        s = fmaf(v, hw[cat * HIDn + lcolbase + cl], s);
      }
      #pragma unroll
      for (int off = 8; off; off >>= 1) s += __shfl_xor(s, off);
      sums[i][rr] = s;
    }
  }
  __syncthreads();
  if ((lane & 15) == 0) {
    #pragma unroll
    for (int i = 0; i < 4; ++i)
      #pragma unroll
      for (int rr = 0; rr < 4; ++rr)
        sm.u.e.plds[wn][lrb + i * 16 + rr] = sums[i][rr];
  }
  __syncthreads();
  if (t < 128) partial[(size_t)bx * Bn + m0 + t] = sm.u.e.plds[0][t] + sm.u.e.plds[1][t];
}

// ====== K3: gate softmax + expert combine + head bias + sigmoid ============
__global__ __launch_bounds__(256) void final_kernel(
    const float* __restrict__ partial, const float* __restrict__ glogp,
    const float* __restrict__ gb2, const int* __restrict__ category,
    const float* __restrict__ hb, float* __restrict__ out) {
  const int row = blockIdx.x * 256 + threadIdx.x;
  const int cat = category[row];
  float gl[5];
  #pragma unroll
  for (int k = 0; k < 5; ++k)
    gl[k] = gb2[cat * 5 + k]
          + glogp[((size_t)0 * Bn + row) * 5 + k]
          + glogp[((size_t)1 * Bn + row) * 5 + k]
          + glogp[((size_t)2 * Bn + row) * 5 + k];
  float mx = fmaxf(fmaxf(fmaxf(gl[0], gl[1]), fmaxf(gl[2], gl[3])), gl[4]);
  float ek[5], es = 0.f;
  #pragma unroll
  for (int k = 0; k < 5; ++k) { ek[k] = __expf(gl[k] - mx); es += ek[k]; }
  const float einv = 1.f / es;
  float s = 0.f;
  #pragma unroll
  for (int k = 0; k < 5; ++k) {
    float ps = partial[(size_t)(3 * k) * Bn + row]
             + partial[(size_t)(3 * k + 1) * Bn + row]
             + partial[(size_t)(3 * k + 2) * Bn + row];
    s = fmaf(ek[k] * einv, ps, s);
  }
  s += hb[cat];
  out[row] = 1.f / (1.f + __expf(-s));
}

extern "C" void kernel_launch(void* const* d_in, const int* in_sizes, int n_in,
                              void* d_out, int out_size, void* d_ws, size_t ws_size,
                              hipStream_t stream) {
  const float* feature  = (const float*)d_in[0];
  const int*   masks    = (const int*)d_in[1];
  const int*   category = (const int*)d_in[2];
  const float* attn_w   = (const float*)d_in[3];
  // d_in[4] attn_b cancels in softmax
  const float* gate_w1  = (const float*)d_in[5];
  const float* gate_b1  = (const float*)d_in[6];
  const float* gate_w2  = (const float*)d_in[7];
  const float* gate_b2  = (const float*)d_in[8];
  const float* expert_w = (const float*)d_in[9];
  const float* expert_b = (const float*)d_in[10];
  const float* head_w   = (const float*)d_in[11];
  const float* head_b   = (const float*)d_in[12];
  float* out = (float*)d_out;

  char* ws = (char*)d_ws;
  unsigned short* pooled = (unsigned short*)(ws);             //  6,291,456 B
  unsigned short* Bpe    = (unsigned short*)(ws + 6291456);   //  2,949,120 B
  unsigned short* Bpg    = (unsigned short*)(ws + 9240576);   //  5,308,416 B
  int* rowsamp           = (int*)(ws + 14548992);             //     20,992 B
  int* meta              = (int*)(ws + 14569984);             //        512 B
  float* glogp           = (float*)(ws + 14570496);           //    245,760 B
  float* partial         = (float*)(ws + 14816256);           //    245,760 B

  prep_kernel<<<dim3(Bn + 2016 + 1), dim3(256), 0, stream>>>(
      feature, masks, attn_w, expert_w, gate_w1, category,
      pooled, Bpe, Bpg, rowsamp, meta);
  gemm_kernel<<<dim3(480 + 3 * MAXTILES), dim3(256), 0, stream>>>(
      pooled, Bpe, Bpg, expert_b, gate_b1, gate_w2, category, head_w,
      rowsamp, meta, partial, glogp);
  final_kernel<<<dim3(16), dim3(256), 0, stream>>>(
      partial, glogp, gate_b2, category, head_b, out);
}